// Round 1
// 765.320 us; speedup vs baseline: 1.1741x; 1.1741x over previous
//
#include <hip/hip_runtime.h>
#include <hip/hip_bf16.h>
#include <type_traits>
#include <utility>

// ---------------------------------------------------------------------------
// C = tril(A @ B), N=8192, A,B lower-triangular fp32.
// convert A->bf16, B->bf16 transposed (lower + diagonal 256-blocks only),
// then bf16 MFMA GEMM over lower 256x256 tiles, K in [bj*256,(bi+1)*256).
// GEMM uses the 256^2 8-phase schedule: 4 rotating K-half LDS slots per
// operand, XOR-swizzled reads (linear global_load_lds dest, inverse-swizzled
// global source), counted s_waitcnt vmcnt(6) at phases 4/8 (never 0 in the
// main loop), raw s_barrier + s_setprio(1) around each 16-MFMA cluster.
// Lower tiles ordered longest-K-first (makespan floor = (31,0) tile).
// ---------------------------------------------------------------------------

static constexpr int MATN = 8192;

typedef __attribute__((ext_vector_type(8))) short  s8v;
typedef __attribute__((ext_vector_type(4))) short  s4h;
typedef __attribute__((ext_vector_type(8))) __bf16 b8v;
typedef __attribute__((ext_vector_type(4))) float  f4v;

template <typename V, typename = void>
struct mfma_ok : std::false_type {};
template <typename V>
struct mfma_ok<V, std::void_t<decltype(__builtin_amdgcn_mfma_f32_16x16x32_bf16(
    std::declval<V>(), std::declval<V>(), std::declval<f4v>(), 0, 0, 0))>>
    : std::true_type {};
using abv = std::conditional_t<mfma_ok<b8v>::value, b8v, s8v>;

__device__ __forceinline__ short f2bf(float f) {
  unsigned u = __builtin_bit_cast(unsigned, f);
  unsigned r = (u + 0x7fffu + ((u >> 16) & 1u)) >> 16;
  return (short)r;
}

__device__ __forceinline__ void async16(void* lds, const void* g) {
  __builtin_amdgcn_global_load_lds(
      (const __attribute__((address_space(1))) unsigned int*)g,
      (__attribute__((address_space(3))) unsigned int*)lds, 16, 0, 0);
}

// largest k with k(k+1)/2 <= id
__device__ __forceinline__ int tri_decode(int id) {
  int k = (int)((sqrtf(8.0f * (float)id + 1.0f) - 1.0f) * 0.5f);
  while ((k + 1) * (k + 2) / 2 <= id) k++;
  while (k * (k + 1) / 2 > id) k--;
  return k;
}

// ---------------------------------------------------------------------------
// Kernel 1: A (fp32) -> Abf (bf16). GEMM reads only lower + diagonal
// 256-blocks of Abf, so upper chunks outside the diagonal block store nothing.
// ---------------------------------------------------------------------------
__global__ __launch_bounds__(256) void convert_A_k(const float* __restrict__ A,
                                                   short* __restrict__ Abf) {
  int gid  = blockIdx.x * 256 + threadIdx.x;
  int base = gid * 8;
  int row  = base >> 13;
  int col  = base & 8191;
  if (col > row && (row >> 8) != (col >> 8)) return;  // never read by GEMM
  s8v o = {};
  if (col <= row) {
    f4v v0 = *(const f4v*)&A[base];
    f4v v1 = *(const f4v*)&A[base + 4];
#pragma unroll
    for (int i = 0; i < 4; i++) { o[i] = f2bf(v0[i]); o[4 + i] = f2bf(v1[i]); }
  }
  *(s8v*)&Abf[base] = o;
}

// ---------------------------------------------------------------------------
// Kernel 2: B (fp32, KxN) -> Bt (bf16, NxK). 64x64 tile via LDS.
// Fully-zero tiles store only when inside a diagonal 256-block.
// ---------------------------------------------------------------------------
__global__ __launch_bounds__(256) void transpose_B_k(const float* __restrict__ B,
                                                     short* __restrict__ Bt) {
  __shared__ __align__(16) short T[64 * 68];
  int k0 = blockIdx.x * 64, n0 = blockIdx.y * 64;
  int tid = threadIdx.x;
  if (k0 + 63 < n0) {                          // Bt tile entirely zero
    if ((k0 >> 8) == (n0 >> 8)) {              // only diag 256-block is read
      s8v z = {};
#pragma unroll
      for (int t = 0; t < 2; t++) {
        int c = t * 256 + tid;
        int n = c >> 3, kg = c & 7;
        *(s8v*)&Bt[(size_t)(n0 + n) * MATN + k0 + kg * 8] = z;
      }
    }
    return;
  }
#pragma unroll
  for (int t = 0; t < 4; t++) {
    int c = t * 256 + tid;
    int k = c >> 4, cn = c & 15;
    s4h o = {};
    if (n0 + cn * 4 <= k0 + k) {               // else structurally zero
      f4v v = *(const f4v*)&B[(size_t)(k0 + k) * MATN + n0 + cn * 4];
#pragma unroll
      for (int i = 0; i < 4; i++) o[i] = f2bf(v[i]);
    }
    int cs = cn ^ (2 * (k >> 3));
    *(s4h*)&T[k * 68 + cs * 4] = o;
  }
  __syncthreads();
#pragma unroll
  for (int t = 0; t < 2; t++) {
    int c = t * 256 + tid;
    int n = c >> 3, kg = c & 7;
    int nn = n ^ (kg * 8);
    s8v o;
#pragma unroll
    for (int i = 0; i < 8; i++) o[i] = T[(kg * 8 + i) * 68 + nn];
    *(s8v*)&Bt[(size_t)(n0 + n) * MATN + k0 + kg * 8] = o;
  }
}

// ---------------------------------------------------------------------------
// 8-phase GEMM helpers.
// LDS map (bytes): A K-half slots s=0..3 at s*16384, B slots at 65536+s*16384.
// Slot = 256 rows x 32 bf16 (row = 64 B). K-tile kt, K-half kk -> slot (2kt+kk)&3.
// Read swizzle: 16B chunk = quad ^ ((ln>>1)&3); write side is linear
// global_load_lds with the inverse swizzle applied to the global source col.
// ---------------------------------------------------------------------------
template <int SA, int C>
__device__ __forceinline__ void lda4(const char* L, int aoff, abv (&a)[4]) {
#pragma unroll
  for (int m = 0; m < 4; m++)
    a[m] = *(const abv*)(L + SA * 16384 + (C * 64 + m * 16) * 64 + aoff);
}
template <int SB>
__device__ __forceinline__ void ldb4(const char* L, int boff, abv (&b)[4]) {
#pragma unroll
  for (int n = 0; n < 4; n++)
    b[n] = *(const abv*)(L + 65536 + SB * 16384 + n * 1024 + boff);
}
template <int C>
__device__ __forceinline__ void mfma16(const abv (&a)[4], const abv (&b)[4],
                                       f4v (&acc)[8][4]) {
#pragma unroll
  for (int m = 0; m < 4; m++)
#pragma unroll
    for (int n = 0; n < 4; n++)
      acc[C * 4 + m][n] = __builtin_amdgcn_mfma_f32_16x16x32_bf16(
          a[m], b[n], acc[C * 4 + m][n], 0, 0, 0);
}
__device__ __forceinline__ void phase_mid() {
  __builtin_amdgcn_sched_barrier(0);
  __builtin_amdgcn_s_barrier();
  __builtin_amdgcn_sched_barrier(0);
  __builtin_amdgcn_s_setprio(1);
}
template <bool VM6>
__device__ __forceinline__ void phase_end() {
  __builtin_amdgcn_s_setprio(0);
  __builtin_amdgcn_sched_barrier(0);
  if constexpr (VM6) asm volatile("s_waitcnt vmcnt(6)" ::: "memory");
  __builtin_amdgcn_s_barrier();
  __builtin_amdgcn_sched_barrier(0);
}

#define STAGE_A(S, KT, KK)                                                   \
  {                                                                          \
    int kc_ = kstart + (KT) * 64 + (KK) * 32 + csw;                          \
    async16(LW + (S) * 16384, Abf + gA + kc_);                               \
    async16(LW + (S) * 16384 + 8192,                                         \
            Abf + gA + (size_t)128 * MATN + kc_);                            \
  }
#define STAGE_B(S, KT, KK)                                                   \
  {                                                                          \
    int kc_ = kstart + (KT) * 64 + (KK) * 32 + csw;                          \
    async16(LW + 65536 + (S) * 16384, Btb + gB + kc_);                       \
    async16(LW + 65536 + (S) * 16384 + 8192,                                 \
            Btb + gB + (size_t)128 * MATN + kc_);                            \
  }

// ---------------------------------------------------------------------------
// Kernel 3: triangular bf16 MFMA GEMM, 256x256 tiles, 512 threads / 8 waves.
// Grid 1024: ids [0,528) lower tiles ordered by descending d=bi-bj (longest
// K first), ids [528,1024) upper tiles -> zero-fill.
// ---------------------------------------------------------------------------
__global__ __launch_bounds__(512) void gemm_tril256(const short* __restrict__ Abf,
                                                    const short* __restrict__ Btb,
                                                    float* __restrict__ C) {
  int id  = blockIdx.x;
  int tid = threadIdx.x;
  int bi, bj;
  if (id < 528) {                              // lower, d descending
    int g = tri_decode(id) + 1;                // id in [tri(g-1), tri(g))
    int j = id - (g - 1) * g / 2;
    bi = j + 32 - g;                           // d = 32-g
    bj = j;
  } else {                                     // upper -> zero fill
    int q = id - 528;
    int r = tri_decode(q);
    bi = q - r * (r + 1) / 2;
    bj = r + 1;
  }

  int row0 = bi << 8, col0 = bj << 8;

  if (bi < bj) {                               // zero tile
    f4v z = {};
    size_t base = (size_t)row0 * MATN + col0;
#pragma unroll
    for (int t = 0; t < 32; t++) {
      int c = t * 512 + tid;
      int r2 = c >> 6, cc = (c & 63) * 4;
      *(f4v*)&C[base + (size_t)r2 * MATN + cc] = z;
    }
    return;
  }

  __shared__ __align__(16) short LDS[65536];   // 128 KiB: A 4 slots + B 4 slots

  int wave = tid >> 6, lane = tid & 63;
  int quad = lane >> 4, ln = lane & 15;
  int wm = wave >> 2, wn = wave & 3;

  const char* L = (const char*)LDS;
  char* LW = (char*)LDS + wave * 1024;         // wave-uniform stage base

  int chunk = (quad ^ ((ln >> 1) & 3)) << 4;   // swizzled 16B chunk (bytes)
  int aoff = (wm * 128 + ln) * 64 + chunk;     // byte offset within A slot
  int boff = (wn * 64 + ln) * 64 + chunk;      // byte offset within B slot

  // inverse swizzle folded into per-lane global source column
  int csw = (((lane & 3) ^ ((lane >> 3) & 3)) << 3);   // element offset
  size_t gA = (size_t)(row0 + wave * 16 + (lane >> 2)) * MATN;
  size_t gB = (size_t)(col0 + wave * 16 + (lane >> 2)) * MATN;

  int kstart = col0;
  int NT = (bi + 1 - bj) << 2;                 // K-tiles of 64; multiple of 4

  f4v acc[8][4] = {};

  // prologue: stage kt0 {A0,B0,A1,B1} + kt1 {A0,B0,B1}; A1(1) staged at p1.
  STAGE_A(0, 0, 0); STAGE_B(0, 0, 0);
  STAGE_A(1, 0, 1); STAGE_B(1, 0, 1);
  STAGE_A(2, 1, 0); STAGE_B(2, 1, 0);
  STAGE_B(3, 1, 1);
  asm volatile("s_waitcnt vmcnt(6)" ::: "memory");   // kt0 fully landed
  __builtin_amdgcn_s_barrier();
  __builtin_amdgcn_sched_barrier(0);

  abv a[4], b[4];
  for (int kt = 0; kt < NT; kt += 2) {
    int k2 = (kt + 2 < NT) ? kt + 2 : 0;       // clamp: data never consumed
    int k3 = (kt + 3 < NT) ? kt + 3 : 0;
    // ---- p1: kt c0 kk0 (A-slot0, B-slot0); stage A1(kt+1) -> A-slot3
    ldb4<0>(L, boff, b);
    lda4<0, 0>(L, aoff, a);
    STAGE_A(3, kt + 1, 1);
    phase_mid(); mfma16<0>(a, b, acc); phase_end<false>();
    // ---- p2: kt c1 kk0 (A-slot0); stage B0(kt+2) -> B-slot0
    lda4<0, 1>(L, aoff, a);
    STAGE_B(0, k2, 0);
    phase_mid(); mfma16<1>(a, b, acc); phase_end<false>();
    // ---- p3: kt c0 kk1 (A-slot1, B-slot1); stage A0(kt+2) -> A-slot0
    ldb4<1>(L, boff, b);
    lda4<1, 0>(L, aoff, a);
    STAGE_A(0, k2, 0);
    phase_mid(); mfma16<0>(a, b, acc); phase_end<false>();
    // ---- p4: kt c1 kk1 (A-slot1); stage B1(kt+2) -> B-slot1; vmcnt(6)
    lda4<1, 1>(L, aoff, a);
    STAGE_B(1, k2, 1);
    phase_mid(); mfma16<1>(a, b, acc); phase_end<true>();
    // ---- p5: kt+1 c0 kk0 (A-slot2, B-slot2); stage A1(kt+2) -> A-slot1
    ldb4<2>(L, boff, b);
    lda4<2, 0>(L, aoff, a);
    STAGE_A(1, k2, 1);
    phase_mid(); mfma16<0>(a, b, acc); phase_end<false>();
    // ---- p6: kt+1 c1 kk0 (A-slot2); stage B0(kt+3) -> B-slot2
    lda4<2, 1>(L, aoff, a);
    STAGE_B(2, k3, 0);
    phase_mid(); mfma16<1>(a, b, acc); phase_end<false>();
    // ---- p7: kt+1 c0 kk1 (A-slot3, B-slot3); stage A0(kt+3) -> A-slot2
    ldb4<3>(L, boff, b);
    lda4<3, 0>(L, aoff, a);
    STAGE_A(2, k3, 0);
    phase_mid(); mfma16<0>(a, b, acc); phase_end<false>();
    // ---- p8: kt+1 c1 kk1 (A-slot3); stage B1(kt+3) -> B-slot3; vmcnt(6)
    lda4<3, 1>(L, aoff, a);
    STAGE_B(3, k3, 1);
    phase_mid(); mfma16<1>(a, b, acc); phase_end<true>();
  }
  asm volatile("s_waitcnt vmcnt(0)" ::: "memory");   // drain tail prefetches

  // epilogue: C/D layout col=lane&15, row=quad*4+reg
  bool diag = (bi == bj);
#pragma unroll
  for (int m = 0; m < 8; m++) {
    int grb = row0 + wm * 128 + m * 16 + quad * 4;
#pragma unroll
    for (int n = 0; n < 4; n++) {
      int gc = col0 + wn * 64 + n * 16 + ln;
#pragma unroll
      for (int r = 0; r < 4; r++) {
        int gr = grb + r;
        float v = acc[m][n][r];
        if (diag && gr < gc) v = 0.0f;
        C[(size_t)gr * MATN + gc] = v;
      }
    }
  }
}

// ---------------------------------------------------------------------------
// Fallback: correct fp32 LDS-tiled GEMM (only if ws too small).
// ---------------------------------------------------------------------------
__global__ __launch_bounds__(256) void gemm_tril_f32(const float* __restrict__ A,
                                                     const float* __restrict__ B,
                                                     float* __restrict__ C) {
  int bj = blockIdx.x, bi = blockIdx.y;
  int tid = threadIdx.x;
  int row0 = bi * 64, col0 = bj * 64;
  if (bi < bj) {
    f4v z = {};
#pragma unroll
    for (int t = 0; t < 4; t++) {
      int c = t * 256 + tid;
      int r = c >> 4, cc = (c & 15) * 4;
      *(f4v*)&C[(size_t)(row0 + r) * MATN + col0 + cc] = z;
    }
    return;
  }
  __shared__ float As[64][17];
  __shared__ float Bs[16][65];
  int tx = tid & 15, ty = tid >> 4;
  float acc[4][4] = {};
  int kendf = (bi + 1) * 64;
  for (int kt = col0; kt < kendf; kt += 16) {
    __syncthreads();
#pragma unroll
    for (int t = 0; t < 4; t++) {
      int c = t * 256 + tid;
      int r = c >> 4, k = c & 15;
      As[r][k] = A[(size_t)(row0 + r) * MATN + kt + k];
    }
#pragma unroll
    for (int t = 0; t < 4; t++) {
      int c = t * 256 + tid;
      int k = c >> 6, n = c & 63;
      Bs[k][n] = B[(size_t)(kt + k) * MATN + col0 + n];
    }
    __syncthreads();
#pragma unroll
    for (int k = 0; k < 16; k++) {
      float av[4], bv[4];
#pragma unroll
      for (int i = 0; i < 4; i++) av[i] = As[ty * 4 + i][k];
#pragma unroll
      for (int j = 0; j < 4; j++) bv[j] = Bs[k][tx * 4 + j];
#pragma unroll
      for (int i = 0; i < 4; i++)
#pragma unroll
        for (int j = 0; j < 4; j++) acc[i][j] += av[i] * bv[j];
    }
  }
#pragma unroll
  for (int i = 0; i < 4; i++)
#pragma unroll
    for (int j = 0; j < 4; j++) {
      int gr = row0 + ty * 4 + i, gc = col0 + tx * 4 + j;
      C[(size_t)gr * MATN + gc] = (gr >= gc) ? acc[i][j] : 0.0f;
    }
}

// ---------------------------------------------------------------------------
extern "C" void kernel_launch(void* const* d_in, const int* in_sizes, int n_in,
                              void* d_out, int out_size, void* d_ws, size_t ws_size,
                              hipStream_t stream) {
  const float* A = (const float*)d_in[0];
  const float* B = (const float*)d_in[1];
  float* C = (float*)d_out;

  const size_t need = 2ull * MATN * MATN * sizeof(short);  // 256 MiB
  if (ws_size >= need) {
    short* Abf = (short*)d_ws;
    short* Btb = Abf + (size_t)MATN * MATN;
    convert_A_k<<<(MATN * (size_t)MATN) / 8 / 256, 256, 0, stream>>>(A, Abf);
    transpose_B_k<<<dim3(MATN / 64, MATN / 64), 256, 0, stream>>>(B, Btb);
    gemm_tril256<<<1024, 512, 0, stream>>>(Abf, Btb, C);
  } else {
    gemm_tril_f32<<<dim3(MATN / 64, MATN / 64), 256, 0, stream>>>(A, B, C);
  }
}